// Round 1
// baseline (342.300 us; speedup 1.0000x reference)
//
#include <hip/hip_runtime.h>

// ---------------------------------------------------------------------------
// HiPPO-LegT via scalar-kernel convolution:
//   pred[b][t] = fac_t * sum_{s<=t} k[t-s] x[b][s] + D x[b][t],  k[tau]=C A^tau B
// k factorized: k[64q+r] = (C A^r) . (A^{64q} B) = W[r] . V[q]
// ---------------------------------------------------------------------------

#define LENGTH 4096
#define NSTATE 256

// ws layout (float offsets)
#define WS_P2    0
#define WS_P4    65536
#define WS_P8    131072
#define WS_P16   196608
#define WS_P32   262144
#define WS_P48   327680
#define WS_P64T  393216
#define WS_W     458752   // 64 x 256
#define WS_K     475136   // 4096

// ---- generic 256x256 matmul: Z[i][j] = sum_l X[i][l] Y[l][j], 256 blocks ----
__global__ __launch_bounds__(256) void mm256(const float* __restrict__ X,
                                             const float* __restrict__ Y,
                                             float* __restrict__ Z) {
    const int i = blockIdx.x, j = threadIdx.x;
    const float* xr = X + i * 256;
    float a0 = 0.f, a1 = 0.f, a2 = 0.f, a3 = 0.f;
#pragma unroll 8
    for (int l = 0; l < 256; l += 4) {
        a0 = fmaf(xr[l + 0], Y[(l + 0) * 256 + j], a0);
        a1 = fmaf(xr[l + 1], Y[(l + 1) * 256 + j], a1);
        a2 = fmaf(xr[l + 2], Y[(l + 2) * 256 + j], a2);
        a3 = fmaf(xr[l + 3], Y[(l + 3) * 256 + j], a3);
    }
    Z[i * 256 + j] = (a0 + a1) + (a2 + a3);
}

// ---- dual launch: blocks 0..255: P64T[j][i] = (P32*P32)[i][j]; 256..511: P48 = P16*P32
__global__ __launch_bounds__(256) void mm_step6(const float* __restrict__ P32,
                                                const float* __restrict__ P16,
                                                float* __restrict__ P64T,
                                                float* __restrict__ P48) {
    const int bb = blockIdx.x, j = threadIdx.x;
    if (bb < 256) {
        const int i = bb;
        const float* xr = P32 + i * 256;
        float a0 = 0.f, a1 = 0.f, a2 = 0.f, a3 = 0.f;
#pragma unroll 8
        for (int l = 0; l < 256; l += 4) {
            a0 = fmaf(xr[l + 0], P32[(l + 0) * 256 + j], a0);
            a1 = fmaf(xr[l + 1], P32[(l + 1) * 256 + j], a1);
            a2 = fmaf(xr[l + 2], P32[(l + 2) * 256 + j], a2);
            a3 = fmaf(xr[l + 3], P32[(l + 3) * 256 + j], a3);
        }
        P64T[j * 256 + i] = (a0 + a1) + (a2 + a3);   // transposed store
    } else {
        const int i = bb - 256;
        const float* xr = P16 + i * 256;
        float a0 = 0.f, a1 = 0.f, a2 = 0.f, a3 = 0.f;
#pragma unroll 8
        for (int l = 0; l < 256; l += 4) {
            a0 = fmaf(xr[l + 0], P32[(l + 0) * 256 + j], a0);
            a1 = fmaf(xr[l + 1], P32[(l + 1) * 256 + j], a1);
            a2 = fmaf(xr[l + 2], P32[(l + 2) * 256 + j], a2);
            a3 = fmaf(xr[l + 3], P32[(l + 3) * 256 + j], a3);
        }
        P48[i * 256 + j] = (a0 + a1) + (a2 + a3);
    }
}

// ---- W generation: block a computes W[16a + r] = C A^{16a+r}, r=0..15 ----
__global__ __launch_bounds__(1024) void wgen(const float* __restrict__ A,
                                             const float* __restrict__ C,
                                             const float* __restrict__ P16,
                                             const float* __restrict__ P32,
                                             const float* __restrict__ P48,
                                             float* __restrict__ W) {
    const int a = blockIdx.x;
    const int t = threadIdx.x;
    const int j = t & 255, p = t >> 8;
    __shared__ float cur[256];
    __shared__ float red[4][256];
    float areg[64];
#pragma unroll
    for (int ii = 0; ii < 64; ++ii) areg[ii] = A[(64 * p + ii) * 256 + j];

    if (a == 0) {
        if (t < 256) cur[t] = C[t];
    } else {
        const float* P = (a == 1) ? P16 : (a == 2) ? P32 : P48;
        float s0 = 0.f, s1 = 0.f, s2 = 0.f, s3 = 0.f;
#pragma unroll 4
        for (int ii = 0; ii < 64; ii += 4) {
            s0 = fmaf(C[64 * p + ii + 0], P[(64 * p + ii + 0) * 256 + j], s0);
            s1 = fmaf(C[64 * p + ii + 1], P[(64 * p + ii + 1) * 256 + j], s1);
            s2 = fmaf(C[64 * p + ii + 2], P[(64 * p + ii + 2) * 256 + j], s2);
            s3 = fmaf(C[64 * p + ii + 3], P[(64 * p + ii + 3) * 256 + j], s3);
        }
        red[p][j] = (s0 + s1) + (s2 + s3);
        __syncthreads();
        if (p == 0) cur[j] = red[0][j] + red[1][j] + red[2][j] + red[3][j];
    }
    __syncthreads();
    if (p == 0) W[(16 * a) * 256 + j] = cur[j];

    for (int r = 1; r < 16; ++r) {
        float s0 = 0.f, s1 = 0.f, s2 = 0.f, s3 = 0.f;
#pragma unroll
        for (int m = 0; m < 16; ++m) {
            float4 c4 = *reinterpret_cast<const float4*>(&cur[64 * p + 4 * m]);
            s0 = fmaf(c4.x, areg[4 * m + 0], s0);
            s1 = fmaf(c4.y, areg[4 * m + 1], s1);
            s2 = fmaf(c4.z, areg[4 * m + 2], s2);
            s3 = fmaf(c4.w, areg[4 * m + 3], s3);
        }
        red[p][j] = (s0 + s1) + (s2 + s3);
        __syncthreads();
        if (p == 0) {
            float s = red[0][j] + red[1][j] + red[2][j] + red[3][j];
            cur[j] = s;
            W[(16 * a + r) * 256 + j] = s;
        }
        __syncthreads();
    }
}

// ---- V chain + dots: cur <- A^64 cur (from B); k[64q+r] = W[r].V[q] ----
__global__ __launch_bounds__(1024) void vgen(const float* __restrict__ MT,
                                             const float* __restrict__ B,
                                             const float* __restrict__ W,
                                             float* __restrict__ K) {
    const int t = threadIdx.x;
    const int i = t & 255, p = t >> 8;
    const int r = t >> 4, h = t & 15;
    __shared__ float cur[256];
    __shared__ float red[4][256];
    float mreg[64];
#pragma unroll
    for (int jj = 0; jj < 64; ++jj) mreg[jj] = MT[(64 * p + jj) * 256 + i];
    if (t < 256) cur[t] = B[t];
    __syncthreads();

    for (int q = 0; q < 64; ++q) {
        // dots for this q
        float pd = 0.f;
#pragma unroll
        for (int jj = 0; jj < 16; ++jj)
            pd = fmaf(W[r * 256 + h * 16 + jj], cur[h * 16 + jj], pd);
#pragma unroll
        for (int off = 8; off >= 1; off >>= 1) pd += __shfl_xor(pd, off, 64);
        if (h == 0) K[q * 64 + r] = pd;
        if (q == 63) break;
        // chain step
        float s0 = 0.f, s1 = 0.f, s2 = 0.f, s3 = 0.f;
#pragma unroll
        for (int m = 0; m < 16; ++m) {
            float4 c4 = *reinterpret_cast<const float4*>(&cur[64 * p + 4 * m]);
            s0 = fmaf(c4.x, mreg[4 * m + 0], s0);
            s1 = fmaf(c4.y, mreg[4 * m + 1], s1);
            s2 = fmaf(c4.z, mreg[4 * m + 2], s2);
            s3 = fmaf(c4.w, mreg[4 * m + 3], s3);
        }
        red[p][i] = (s0 + s1) + (s2 + s3);
        __syncthreads();
        if (p == 0) cur[i] = red[0][i] + red[1][i] + red[2][i] + red[3][i];
        __syncthreads();
    }
}

// ---- causal conv: out[b][t] = fac_t * sum_s k[t-s] x[b][s] + D x[b][t] ----
// tile: 64 t  x 32 b per block; thread: 4 consecutive t x 2 b; grid (64, 8)
__global__ __launch_bounds__(256) void conv(const float* __restrict__ x,
                                            const float* __restrict__ K,
                                            const float* __restrict__ Dp,
                                            float* __restrict__ out) {
    const int t0 = blockIdx.x * 64;
    const int b0 = blockIdx.y * 32;
    const int tid = threadIdx.x;
    const int tq = tid & 15, bq = tid >> 4;     // compute mapping
    const int st_s = tid & 15, st_b = tid >> 4; // staging mapping
    __shared__ __align__(16) float xs[64][68];  // [s][b], stride 68 for aligned b64 reads
    __shared__ __align__(16) float ks[136];
    float acc[4][2] = {};
    const float D = Dp[0];

    for (int sc = 0; sc <= t0; sc += 64) {
        __syncthreads();
        // stage x tile transposed: thread loads 2 rows x 4 cols
        float4 xa = *reinterpret_cast<const float4*>(&x[(b0 + 2 * st_b + 0) * LENGTH + sc + 4 * st_s]);
        float4 xb = *reinterpret_cast<const float4*>(&x[(b0 + 2 * st_b + 1) * LENGTH + sc + 4 * st_s]);
        *reinterpret_cast<float2*>(&xs[4 * st_s + 0][2 * st_b]) = make_float2(xa.x, xb.x);
        *reinterpret_cast<float2*>(&xs[4 * st_s + 1][2 * st_b]) = make_float2(xa.y, xb.y);
        *reinterpret_cast<float2*>(&xs[4 * st_s + 2][2 * st_b]) = make_float2(xa.z, xb.z);
        *reinterpret_cast<float2*>(&xs[4 * st_s + 3][2 * st_b]) = make_float2(xa.w, xb.w);
        // stage k lag-window: ks[d] = K[t0 - sc - 63 + d], 0 outside [0,4096)
        if (tid < 136) {
            int idx = t0 - sc - 63 + tid;
            ks[tid] = (tid < 128 && idx >= 0 && idx < LENGTH) ? K[idx] : 0.f;
        }
        __syncthreads();
#pragma unroll
        for (int g = 0; g < 16; ++g) {
            const int base = 4 * tq + 60 - 4 * g;
            float4 w0 = *reinterpret_cast<const float4*>(&ks[base]);
            float4 w1 = *reinterpret_cast<const float4*>(&ks[base + 4]);
            float w[8] = {w0.x, w0.y, w0.z, w0.w, w1.x, w1.y, w1.z, w1.w};
#pragma unroll
            for (int u = 0; u < 4; ++u) {
                float2 xv = *reinterpret_cast<const float2*>(&xs[4 * g + u][2 * bq]);
#pragma unroll
                for (int i2 = 0; i2 < 4; ++i2) {
                    acc[i2][0] = fmaf(w[3 - u + i2], xv.x, acc[i2][0]);
                    acc[i2][1] = fmaf(w[3 - u + i2], xv.y, acc[i2][1]);
                }
            }
        }
    }
#pragma unroll
    for (int i2 = 0; i2 < 4; ++i2) {
        const int tt = t0 + 4 * tq + i2;
        const float fac = (tt == 0) ? 1.0f : 2.0f;
#pragma unroll
        for (int j = 0; j < 2; ++j) {
            const int b = b0 + 2 * bq + j;
            const float xv = x[b * LENGTH + tt];
            out[b * LENGTH + tt] = fmaf(fac, acc[i2][j], D * xv);
        }
    }
}

extern "C" void kernel_launch(void* const* d_in, const int* in_sizes, int n_in,
                              void* d_out, int out_size, void* d_ws, size_t ws_size,
                              hipStream_t stream) {
    const float* x  = (const float*)d_in[0];
    const float* A  = (const float*)d_in[1];
    const float* B  = (const float*)d_in[2];
    const float* C  = (const float*)d_in[3];
    const float* Dp = (const float*)d_in[4];
    float* out = (float*)d_out;
    float* ws  = (float*)d_ws;

    float* P2   = ws + WS_P2;
    float* P4   = ws + WS_P4;
    float* P8   = ws + WS_P8;
    float* P16  = ws + WS_P16;
    float* P32  = ws + WS_P32;
    float* P48  = ws + WS_P48;
    float* P64T = ws + WS_P64T;
    float* Wm   = ws + WS_W;
    float* K    = ws + WS_K;

    mm256<<<256, 256, 0, stream>>>(A, A, P2);
    mm256<<<256, 256, 0, stream>>>(P2, P2, P4);
    mm256<<<256, 256, 0, stream>>>(P4, P4, P8);
    mm256<<<256, 256, 0, stream>>>(P8, P8, P16);
    mm256<<<256, 256, 0, stream>>>(P16, P16, P32);
    mm_step6<<<512, 256, 0, stream>>>(P32, P16, P64T, P48);
    wgen<<<4, 1024, 0, stream>>>(A, C, P16, P32, P48, Wm);
    vgen<<<1, 1024, 0, stream>>>(P64T, B, Wm, K);
    conv<<<dim3(64, 8), 256, 0, stream>>>(x, K, Dp, out);
}

// Round 2
// 179.554 us; speedup vs baseline: 1.9064x; 1.9064x over previous
//
#include <hip/hip_runtime.h>

// ---------------------------------------------------------------------------
// HiPPO-LegT via scalar-kernel convolution:
//   pred[b][t] = fac_t * sum_{s<=t} k[t-s] x[b][s] + D x[b][t],  k[tau]=C A^tau B
// k factorized: k[64q+r] = (C A^r) . (A^{64q} B) = W[r] . V[q]
// ---------------------------------------------------------------------------

#define LENGTH 4096
#define NSTATE 256
#define XSTRIDE 76   // floats; 76*4B=304B == 48 mod 128 -> conflict-light b128

// ws layout (float offsets)
#define WS_P2    0
#define WS_P4    65536
#define WS_P8    131072
#define WS_P16   196608
#define WS_P32   262144
#define WS_P48   327680
#define WS_P64T  393216
#define WS_W     458752   // 64 x 256
#define WS_V     475136   // 64 x 256
#define WS_K     491520   // 4096

// ---- zero d_out (atomics accumulate into it) ----
__global__ __launch_bounds__(256) void zerok(float4* __restrict__ out) {
    out[blockIdx.x * 256 + threadIdx.x] = float4{0.f, 0.f, 0.f, 0.f};
}

// ---- 256x256 matmul, one row per block, K split over 4 thread-groups ----
__global__ __launch_bounds__(1024) void mmrow(const float* __restrict__ X,
                                              const float* __restrict__ Y,
                                              float* __restrict__ Z) {
    const int i = blockIdx.x, t = threadIdx.x;
    const int j = t & 255, p = t >> 8;
    __shared__ float red[3][256];
    const float* xr = X + i * 256 + 64 * p;
    const float* yc = Y + (64 * p) * 256 + j;
    float a0 = 0.f, a1 = 0.f, a2 = 0.f, a3 = 0.f;
#pragma unroll
    for (int l = 0; l < 64; l += 4) {
        a0 = fmaf(xr[l + 0], yc[(l + 0) * 256], a0);
        a1 = fmaf(xr[l + 1], yc[(l + 1) * 256], a1);
        a2 = fmaf(xr[l + 2], yc[(l + 2) * 256], a2);
        a3 = fmaf(xr[l + 3], yc[(l + 3) * 256], a3);
    }
    float s = (a0 + a1) + (a2 + a3);
    if (p) red[p - 1][j] = s;
    __syncthreads();
    if (p == 0) Z[i * 256 + j] = s + red[0][j] + red[1][j] + red[2][j];
}

// ---- dual: blocks 0..255: P64T[j][i] = (P32*P32)[i][j]; 256..511: P48 = P16*P32
__global__ __launch_bounds__(1024) void mm2(const float* __restrict__ P32,
                                            const float* __restrict__ P16,
                                            float* __restrict__ P64T,
                                            float* __restrict__ P48) {
    const int bb = blockIdx.x, t = threadIdx.x;
    const int j = t & 255, p = t >> 8;
    __shared__ float red[3][256];
    const int i = (bb < 256) ? bb : bb - 256;
    const float* xr = ((bb < 256) ? P32 : P16) + i * 256 + 64 * p;
    const float* yc = P32 + (64 * p) * 256 + j;
    float a0 = 0.f, a1 = 0.f, a2 = 0.f, a3 = 0.f;
#pragma unroll
    for (int l = 0; l < 64; l += 4) {
        a0 = fmaf(xr[l + 0], yc[(l + 0) * 256], a0);
        a1 = fmaf(xr[l + 1], yc[(l + 1) * 256], a1);
        a2 = fmaf(xr[l + 2], yc[(l + 2) * 256], a2);
        a3 = fmaf(xr[l + 3], yc[(l + 3) * 256], a3);
    }
    float s = (a0 + a1) + (a2 + a3);
    if (p) red[p - 1][j] = s;
    __syncthreads();
    if (p == 0) {
        float z = s + red[0][j] + red[1][j] + red[2][j];
        if (bb < 256) P64T[j * 256 + i] = z;   // transposed store
        else          P48[i * 256 + j] = z;
    }
}

// ---- fused: blocks 0..3 = W rows (C A^{16a+r}); block 4 = V chain (A^{64q} B)
__global__ __launch_bounds__(1024) void wvgen(const float* __restrict__ A,
                                              const float* __restrict__ B,
                                              const float* __restrict__ C,
                                              const float* __restrict__ P16,
                                              const float* __restrict__ P32,
                                              const float* __restrict__ P48,
                                              const float* __restrict__ P64T,
                                              float* __restrict__ W,
                                              float* __restrict__ V) {
    const int t = threadIdx.x;
    __shared__ float cur[256];
    __shared__ float red[4][256];

    if (blockIdx.x < 4) {
        // ---------------- W generation ----------------
        const int a = blockIdx.x;
        const int j = t & 255, p = t >> 8;
        float areg[64];
#pragma unroll
        for (int ii = 0; ii < 64; ++ii) areg[ii] = A[(64 * p + ii) * 256 + j];

        if (a == 0) {
            if (t < 256) cur[t] = C[t];
        } else {
            const float* P = (a == 1) ? P16 : (a == 2) ? P32 : P48;
            float s0 = 0.f, s1 = 0.f, s2 = 0.f, s3 = 0.f;
#pragma unroll 4
            for (int ii = 0; ii < 64; ii += 4) {
                s0 = fmaf(C[64 * p + ii + 0], P[(64 * p + ii + 0) * 256 + j], s0);
                s1 = fmaf(C[64 * p + ii + 1], P[(64 * p + ii + 1) * 256 + j], s1);
                s2 = fmaf(C[64 * p + ii + 2], P[(64 * p + ii + 2) * 256 + j], s2);
                s3 = fmaf(C[64 * p + ii + 3], P[(64 * p + ii + 3) * 256 + j], s3);
            }
            red[p][j] = (s0 + s1) + (s2 + s3);
            __syncthreads();
            if (p == 0) cur[j] = red[0][j] + red[1][j] + red[2][j] + red[3][j];
        }
        __syncthreads();
        if (p == 0) W[(16 * a) * 256 + j] = cur[j];

        for (int r = 1; r < 16; ++r) {
            float s0 = 0.f, s1 = 0.f, s2 = 0.f, s3 = 0.f;
#pragma unroll
            for (int m = 0; m < 16; ++m) {
                float4 c4 = *reinterpret_cast<const float4*>(&cur[64 * p + 4 * m]);
                s0 = fmaf(c4.x, areg[4 * m + 0], s0);
                s1 = fmaf(c4.y, areg[4 * m + 1], s1);
                s2 = fmaf(c4.z, areg[4 * m + 2], s2);
                s3 = fmaf(c4.w, areg[4 * m + 3], s3);
            }
            red[p][j] = (s0 + s1) + (s2 + s3);
            __syncthreads();
            if (p == 0) {
                float s = red[0][j] + red[1][j] + red[2][j] + red[3][j];
                cur[j] = s;
                W[(16 * a + r) * 256 + j] = s;
            }
            __syncthreads();
        }
    } else {
        // ---------------- V chain ----------------
        const int i = t & 255, p = t >> 8;
        float mreg[64];
#pragma unroll
        for (int jj = 0; jj < 64; ++jj) mreg[jj] = P64T[(64 * p + jj) * 256 + i];
        if (t < 256) cur[t] = B[t];
        __syncthreads();

        for (int q = 0; q < 64; ++q) {
            if (p == 0) V[q * 256 + i] = cur[i];
            if (q == 63) break;
            float s0 = 0.f, s1 = 0.f, s2 = 0.f, s3 = 0.f;
#pragma unroll
            for (int m = 0; m < 16; ++m) {
                float4 c4 = *reinterpret_cast<const float4*>(&cur[64 * p + 4 * m]);
                s0 = fmaf(c4.x, mreg[4 * m + 0], s0);
                s1 = fmaf(c4.y, mreg[4 * m + 1], s1);
                s2 = fmaf(c4.z, mreg[4 * m + 2], s2);
                s3 = fmaf(c4.w, mreg[4 * m + 3], s3);
            }
            red[p][i] = (s0 + s1) + (s2 + s3);
            __syncthreads();
            if (p == 0) cur[i] = red[0][i] + red[1][i] + red[2][i] + red[3][i];
            __syncthreads();
        }
    }
}

// ---- K dots: K[64q + r] = W[r] . V[q], block = q ----
__global__ __launch_bounds__(256) void kdot(const float* __restrict__ W,
                                            const float* __restrict__ V,
                                            float* __restrict__ K) {
    const int q = blockIdx.x, tid = threadIdx.x;
    const int r = tid & 63, p = tid >> 6;
    __shared__ float Wl[64 * 257];
    __shared__ float Vl[256];
    __shared__ float red[4][64];
    for (int u = 0; u < 64; ++u) Wl[u * 257 + tid] = W[u * 256 + tid];
    Vl[tid] = V[q * 256 + tid];
    __syncthreads();
    float s0 = 0.f, s1 = 0.f;
#pragma unroll
    for (int m = 0; m < 64; m += 2) {
        s0 = fmaf(Wl[r * 257 + 64 * p + m + 0], Vl[64 * p + m + 0], s0);
        s1 = fmaf(Wl[r * 257 + 64 * p + m + 1], Vl[64 * p + m + 1], s1);
    }
    red[p][r] = s0 + s1;
    __syncthreads();
    if (tid < 64) K[q * 64 + tid] = red[0][tid] + red[1][tid] + red[2][tid] + red[3][tid];
}

// ---- causal conv, balanced: pair (i, 63-i) t-tiles, 65 chunks / 4 quarters ----
// block tile: 64t x 64b, thread: 4t x 4b. grid = 32 pairs * 4 btiles * 4 quarters
__global__ __launch_bounds__(256) void conv(const float* __restrict__ x,
                                            const float* __restrict__ K,
                                            const float* __restrict__ Dp,
                                            float* __restrict__ out) {
    const int bx = blockIdx.x;
    const int pr = bx & 31;           // pair
    const int j  = (bx >> 5) & 3;     // b-tile
    const int h  = bx >> 7;           // quarter
    const int b0 = j * 64;
    const int tid = threadIdx.x;
    const int tq = tid & 15, bq = tid >> 4;
    const int srow = tid >> 2, sseg = tid & 3;   // staging: row = b, seg = s

    __shared__ __align__(16) float xs[64 * XSTRIDE];  // [b][s]
    __shared__ __align__(16) float ks[128];

    const int tileA = pr, tileB = 63 - pr;
    const int nA = tileA + 1;
    const int lo = (65 * h) >> 2;
    const int hi = (65 * (h + 1)) >> 2;
    const float D = Dp[0];

    float acc[4][4] = {};   // [ti][u(b)]
    int cur_tile = -1;

    for (int idx = lo; idx < hi; ++idx) {
        const int tile = (idx < nA) ? tileA : tileB;
        const int c    = (idx < nA) ? idx   : idx - nA;
        const int t0 = tile * 64;
        const int sc = c * 64;

        if (tile != cur_tile) {
            if (cur_tile >= 0) {
                const int ft0 = cur_tile * 64;
#pragma unroll
                for (int ti = 0; ti < 4; ++ti)
#pragma unroll
                    for (int u = 0; u < 4; ++u) {
                        atomicAdd(&out[(b0 + 4 * bq + u) * LENGTH + ft0 + 4 * tq + ti],
                                  2.0f * acc[ti][u]);
                        acc[ti][u] = 0.f;
                    }
            }
            cur_tile = tile;
        }

        __syncthreads();
        {   // stage x[b0+srow][sc + 16*sseg .. +15]
            const float* xsrc = &x[(b0 + srow) * LENGTH + sc + 16 * sseg];
            float4 v0 = reinterpret_cast<const float4*>(xsrc)[0];
            float4 v1 = reinterpret_cast<const float4*>(xsrc)[1];
            float4 v2 = reinterpret_cast<const float4*>(xsrc)[2];
            float4 v3 = reinterpret_cast<const float4*>(xsrc)[3];
            float* xd = &xs[srow * XSTRIDE + 16 * sseg];
            reinterpret_cast<float4*>(xd)[0] = v0;
            reinterpret_cast<float4*>(xd)[1] = v1;
            reinterpret_cast<float4*>(xd)[2] = v2;
            reinterpret_cast<float4*>(xd)[3] = v3;
        }
        if (tid < 128) {
            const int kidx = t0 - sc - 64 + tid;   // lag = t0-sc + (tid-64)
            ks[tid] = (kidx >= 0 && kidx < LENGTH) ? K[kidx] : 0.f;
        }
        __syncthreads();

        // inner: lag = (t0-sc) + 4tq - 4g + ti - si;  ks[d]=K[lag], d0=64+4(tq-g)
        float4 whi = *reinterpret_cast<const float4*>(&ks[64 + 4 * tq]);
        float4 wlo = *reinterpret_cast<const float4*>(&ks[60 + 4 * tq]);
#pragma unroll
        for (int g = 0; g < 16; ++g) {
            const float w[8] = {wlo.x, wlo.y, wlo.z, wlo.w, whi.x, whi.y, whi.z, whi.w};
            float4 wnext = {0.f, 0.f, 0.f, 0.f};
            if (g < 15) wnext = *reinterpret_cast<const float4*>(&ks[56 + 4 * tq - 4 * g]);
#pragma unroll
            for (int u = 0; u < 4; ++u) {
                const float4 xv = *reinterpret_cast<const float4*>(&xs[(4 * bq + u) * XSTRIDE + 4 * g]);
#pragma unroll
                for (int ti = 0; ti < 4; ++ti) {
                    acc[ti][u] = fmaf(w[4 + ti], xv.x, acc[ti][u]);   // si=0
                    acc[ti][u] = fmaf(w[3 + ti], xv.y, acc[ti][u]);   // si=1
                    acc[ti][u] = fmaf(w[2 + ti], xv.z, acc[ti][u]);   // si=2
                    acc[ti][u] = fmaf(w[1 + ti], xv.w, acc[ti][u]);   // si=3
                }
            }
            whi = wlo; wlo = wnext;
        }

        // diagonal chunk: fold D*x (and fac=1 fix for t==0); acc scaled 2x at flush
        if (sc == t0) {
            const float K0 = ks[64];
#pragma unroll
            for (int ti = 0; ti < 4; ++ti) {
                const int tt = t0 + 4 * tq + ti;
#pragma unroll
                for (int u = 0; u < 4; ++u) {
                    const float xv = xs[(4 * bq + u) * XSTRIDE + 4 * tq + ti];
                    float e = D * xv;
                    if (tt == 0) e -= K0 * xv;
                    acc[ti][u] += 0.5f * e;
                }
            }
        }
    }

    if (cur_tile >= 0) {
        const int ft0 = cur_tile * 64;
#pragma unroll
        for (int ti = 0; ti < 4; ++ti)
#pragma unroll
            for (int u = 0; u < 4; ++u)
                atomicAdd(&out[(b0 + 4 * bq + u) * LENGTH + ft0 + 4 * tq + ti],
                          2.0f * acc[ti][u]);
    }
}

extern "C" void kernel_launch(void* const* d_in, const int* in_sizes, int n_in,
                              void* d_out, int out_size, void* d_ws, size_t ws_size,
                              hipStream_t stream) {
    const float* x  = (const float*)d_in[0];
    const float* A  = (const float*)d_in[1];
    const float* B  = (const float*)d_in[2];
    const float* C  = (const float*)d_in[3];
    const float* Dp = (const float*)d_in[4];
    float* out = (float*)d_out;
    float* ws  = (float*)d_ws;

    float* P2   = ws + WS_P2;
    float* P4   = ws + WS_P4;
    float* P8   = ws + WS_P8;
    float* P16  = ws + WS_P16;
    float* P32  = ws + WS_P32;
    float* P48  = ws + WS_P48;
    float* P64T = ws + WS_P64T;
    float* Wm   = ws + WS_W;
    float* Vm   = ws + WS_V;
    float* K    = ws + WS_K;

    zerok<<<out_size / 1024, 256, 0, stream>>>((float4*)out);
    mmrow<<<256, 1024, 0, stream>>>(A, A, P2);
    mmrow<<<256, 1024, 0, stream>>>(P2, P2, P4);
    mmrow<<<256, 1024, 0, stream>>>(P4, P4, P8);
    mmrow<<<256, 1024, 0, stream>>>(P8, P8, P16);
    mmrow<<<256, 1024, 0, stream>>>(P16, P16, P32);
    mm2<<<512, 1024, 0, stream>>>(P32, P16, P64T, P48);
    wvgen<<<5, 1024, 0, stream>>>(A, B, C, P16, P32, P48, P64T, Wm, Vm);
    kdot<<<64, 256, 0, stream>>>(Wm, Vm, K);
    conv<<<512, 256, 0, stream>>>(x, K, Dp, out);
}

// Round 3
// 176.781 us; speedup vs baseline: 1.9363x; 1.0157x over previous
//
#include <hip/hip_runtime.h>

// ---------------------------------------------------------------------------
// HiPPO-LegT via scalar-kernel convolution:
//   pred[b][t] = fac_t * sum_{s<=t} k[t-s] x[b][s] + D x[b][t],  k[tau]=C A^tau B
// k factorized: k[64q+r] = (C A^r) . (A^{64q} B) = W[r] . V[q]
// Conv as MFMA GEMM: out[t][b] = sum_s T[t][s] x[s][b], T Toeplitz from k.
// A-fragments (Toeplitz, bf16 hi+lo) precomputed per lag d0=16m (256 entries);
// x pre-packed transposed into B-fragment layout (bf16 hi+lo).
// ---------------------------------------------------------------------------

#define LENGTH 4096

// ws layout (float offsets)
#define WS_P2    0
#define WS_P4    65536
#define WS_P8    131072
#define WS_P16   196608
#define WS_P32   262144
#define WS_P48   327680
#define WS_P64T  393216
#define WS_W     458752   // 64 x 256
#define WS_V     475136   // 64 x 256
#define WS_K     491520   // 4096
#define WS_XH    495616   // 1M shorts = 524288 floats
#define WS_XL    1019904
#define WS_AH    1544192  // 256*64*8 shorts = 65536 floats
#define WS_AL    1609728

typedef __attribute__((ext_vector_type(8))) short bf16x8;
typedef __attribute__((ext_vector_type(4))) float f32x4;
#define MFMA(a, b, c) __builtin_amdgcn_mfma_f32_16x16x32_bf16(a, b, c, 0, 0, 0)

__device__ inline unsigned short f2bf(float f) {
    unsigned int u = __float_as_uint(f);
    return (unsigned short)((u + 0x7FFFu + ((u >> 16) & 1u)) >> 16);
}
__device__ inline void split2(float f, short& h, short& l) {
    unsigned short hu = f2bf(f);
    float fh = __uint_as_float((unsigned int)hu << 16);
    h = (short)hu;
    l = (short)f2bf(f - fh);
}

// ---- 256x256 matmul, one row per block, K split over 4 thread-groups ----
__global__ __launch_bounds__(1024) void mmrow(const float* __restrict__ X,
                                              const float* __restrict__ Y,
                                              float* __restrict__ Z) {
    const int i = blockIdx.x, t = threadIdx.x;
    const int j = t & 255, p = t >> 8;
    __shared__ float red[3][256];
    const float* xr = X + i * 256 + 64 * p;
    const float* yc = Y + (64 * p) * 256 + j;
    float a0 = 0.f, a1 = 0.f, a2 = 0.f, a3 = 0.f;
#pragma unroll
    for (int l = 0; l < 64; l += 4) {
        a0 = fmaf(xr[l + 0], yc[(l + 0) * 256], a0);
        a1 = fmaf(xr[l + 1], yc[(l + 1) * 256], a1);
        a2 = fmaf(xr[l + 2], yc[(l + 2) * 256], a2);
        a3 = fmaf(xr[l + 3], yc[(l + 3) * 256], a3);
    }
    float s = (a0 + a1) + (a2 + a3);
    if (p) red[p - 1][j] = s;
    __syncthreads();
    if (p == 0) Z[i * 256 + j] = s + red[0][j] + red[1][j] + red[2][j];
}

// ---- dual: blocks 0..255: P64T[j][i] = (P32*P32)[i][j]; 256..511: P48 = P16*P32
__global__ __launch_bounds__(1024) void mm2(const float* __restrict__ P32,
                                            const float* __restrict__ P16,
                                            float* __restrict__ P64T,
                                            float* __restrict__ P48) {
    const int bb = blockIdx.x, t = threadIdx.x;
    const int j = t & 255, p = t >> 8;
    __shared__ float red[3][256];
    const int i = (bb < 256) ? bb : bb - 256;
    const float* xr = ((bb < 256) ? P32 : P16) + i * 256 + 64 * p;
    const float* yc = P32 + (64 * p) * 256 + j;
    float a0 = 0.f, a1 = 0.f, a2 = 0.f, a3 = 0.f;
#pragma unroll
    for (int l = 0; l < 64; l += 4) {
        a0 = fmaf(xr[l + 0], yc[(l + 0) * 256], a0);
        a1 = fmaf(xr[l + 1], yc[(l + 1) * 256], a1);
        a2 = fmaf(xr[l + 2], yc[(l + 2) * 256], a2);
        a3 = fmaf(xr[l + 3], yc[(l + 3) * 256], a3);
    }
    float s = (a0 + a1) + (a2 + a3);
    if (p) red[p - 1][j] = s;
    __syncthreads();
    if (p == 0) {
        float z = s + red[0][j] + red[1][j] + red[2][j];
        if (bb < 256) P64T[j * 256 + i] = z;   // transposed store
        else          P48[i * 256 + j] = z;
    }
}

// ---- fused: blocks 0..3 = W rows (C A^{16a+r}); block 4 = V chain (A^{64q} B)
__global__ __launch_bounds__(1024) void wvgen(const float* __restrict__ A,
                                              const float* __restrict__ B,
                                              const float* __restrict__ C,
                                              const float* __restrict__ P16,
                                              const float* __restrict__ P32,
                                              const float* __restrict__ P48,
                                              const float* __restrict__ P64T,
                                              float* __restrict__ W,
                                              float* __restrict__ V) {
    const int t = threadIdx.x;
    __shared__ float cur[256];
    __shared__ float red[4][256];

    if (blockIdx.x < 4) {
        const int a = blockIdx.x;
        const int j = t & 255, p = t >> 8;
        float areg[64];
#pragma unroll
        for (int ii = 0; ii < 64; ++ii) areg[ii] = A[(64 * p + ii) * 256 + j];

        if (a == 0) {
            if (t < 256) cur[t] = C[t];
        } else {
            const float* P = (a == 1) ? P16 : (a == 2) ? P32 : P48;
            float s0 = 0.f, s1 = 0.f, s2 = 0.f, s3 = 0.f;
#pragma unroll 4
            for (int ii = 0; ii < 64; ii += 4) {
                s0 = fmaf(C[64 * p + ii + 0], P[(64 * p + ii + 0) * 256 + j], s0);
                s1 = fmaf(C[64 * p + ii + 1], P[(64 * p + ii + 1) * 256 + j], s1);
                s2 = fmaf(C[64 * p + ii + 2], P[(64 * p + ii + 2) * 256 + j], s2);
                s3 = fmaf(C[64 * p + ii + 3], P[(64 * p + ii + 3) * 256 + j], s3);
            }
            red[p][j] = (s0 + s1) + (s2 + s3);
            __syncthreads();
            if (p == 0) cur[j] = red[0][j] + red[1][j] + red[2][j] + red[3][j];
        }
        __syncthreads();
        if (p == 0) W[(16 * a) * 256 + j] = cur[j];

        for (int r = 1; r < 16; ++r) {
            float s0 = 0.f, s1 = 0.f, s2 = 0.f, s3 = 0.f;
#pragma unroll
            for (int m = 0; m < 16; ++m) {
                float4 c4 = *reinterpret_cast<const float4*>(&cur[64 * p + 4 * m]);
                s0 = fmaf(c4.x, areg[4 * m + 0], s0);
                s1 = fmaf(c4.y, areg[4 * m + 1], s1);
                s2 = fmaf(c4.z, areg[4 * m + 2], s2);
                s3 = fmaf(c4.w, areg[4 * m + 3], s3);
            }
            red[p][j] = (s0 + s1) + (s2 + s3);
            __syncthreads();
            if (p == 0) {
                float s = red[0][j] + red[1][j] + red[2][j] + red[3][j];
                cur[j] = s;
                W[(16 * a + r) * 256 + j] = s;
            }
            __syncthreads();
        }
    } else {
        const int i = t & 255, p = t >> 8;
        float mreg[64];
#pragma unroll
        for (int jj = 0; jj < 64; ++jj) mreg[jj] = P64T[(64 * p + jj) * 256 + i];
        if (t < 256) cur[t] = B[t];
        __syncthreads();

        for (int q = 0; q < 64; ++q) {
            if (p == 0) V[q * 256 + i] = cur[i];
            if (q == 63) break;
            float s0 = 0.f, s1 = 0.f, s2 = 0.f, s3 = 0.f;
#pragma unroll
            for (int m = 0; m < 16; ++m) {
                float4 c4 = *reinterpret_cast<const float4*>(&cur[64 * p + 4 * m]);
                s0 = fmaf(c4.x, mreg[4 * m + 0], s0);
                s1 = fmaf(c4.y, mreg[4 * m + 1], s1);
                s2 = fmaf(c4.z, mreg[4 * m + 2], s2);
                s3 = fmaf(c4.w, mreg[4 * m + 3], s3);
            }
            red[p][i] = (s0 + s1) + (s2 + s3);
            __syncthreads();
            if (p == 0) cur[i] = red[0][i] + red[1][i] + red[2][i] + red[3][i];
            __syncthreads();
        }
    }
}

// ---- K dots: K[64q + r] = W[r] . V[q], block = q ----
__global__ __launch_bounds__(256) void kdot(const float* __restrict__ W,
                                            const float* __restrict__ V,
                                            float* __restrict__ K) {
    const int q = blockIdx.x, tid = threadIdx.x;
    const int r = tid & 63, p = tid >> 6;
    __shared__ float Wl[64 * 257];
    __shared__ float Vl[256];
    __shared__ float red[4][64];
    for (int u = 0; u < 64; ++u) Wl[u * 257 + tid] = W[u * 256 + tid];
    Vl[tid] = V[q * 256 + tid];
    __syncthreads();
    float s0 = 0.f, s1 = 0.f;
#pragma unroll
    for (int m = 0; m < 64; m += 2) {
        s0 = fmaf(Wl[r * 257 + 64 * p + m + 0], Vl[64 * p + m + 0], s0);
        s1 = fmaf(Wl[r * 257 + 64 * p + m + 1], Vl[64 * p + m + 1], s1);
    }
    red[p][r] = s0 + s1;
    __syncthreads();
    if (tid < 64) K[q * 64 + tid] = red[0][tid] + red[1][tid] + red[2][tid] + red[3][tid];
}

// ---- pack x into B-fragment layout, bf16 hi+lo ----
// XH[((c*16+blk)*64+lane)*8+e] = bf16(x[blk*16+(lane&15)][c*32+8*(lane>>4)+e])
__global__ __launch_bounds__(256) void xsplit(const float* __restrict__ x,
                                              short* __restrict__ XH,
                                              short* __restrict__ XL) {
    const int w = threadIdx.x >> 6, lane = threadIdx.x & 63;
    const int p = blockIdx.x * 4 + w;          // 0..2047
    const int c = p >> 4, blk = p & 15;
    const int b = blk * 16 + (lane & 15);
    const int s0 = c * 32 + 8 * (lane >> 4);
    const float4 v0 = reinterpret_cast<const float4*>(&x[b * LENGTH + s0])[0];
    const float4 v1 = reinterpret_cast<const float4*>(&x[b * LENGTH + s0])[1];
    const float f[8] = {v0.x, v0.y, v0.z, v0.w, v1.x, v1.y, v1.z, v1.w};
    bf16x8 hv, lv;
#pragma unroll
    for (int e = 0; e < 8; ++e) {
        short h, l;
        split2(f[e], h, l);
        hv[e] = h; lv[e] = l;
    }
    const int off = (p * 64 + lane) * 8;
    *reinterpret_cast<bf16x8*>(XH + off) = hv;
    *reinterpret_cast<bf16x8*>(XL + off) = lv;
}

// ---- Toeplitz A-fragment tables: entry m = lag d0 = 16m ----
// AH[(m*64+lane)*8+e] = bf16(k[16m + (lane&15) - 8*(lane>>4) - e]), 0 if idx<0
__global__ __launch_bounds__(256) void afrag(const float* __restrict__ K,
                                             short* __restrict__ AH,
                                             short* __restrict__ AL) {
    const int m = blockIdx.x * 4 + (threadIdx.x >> 6);
    const int lane = threadIdx.x & 63;
    bf16x8 hv, lv;
#pragma unroll
    for (int e = 0; e < 8; ++e) {
        const int kidx = 16 * m + (lane & 15) - 8 * (lane >> 4) - e;
        const float kv = (kidx >= 0) ? K[kidx] : 0.f;
        short h, l;
        split2(kv, h, l);
        hv[e] = h; lv[e] = l;
    }
    const int off = (m * 64 + lane) * 8;
    *reinterpret_cast<bf16x8*>(AH + off) = hv;
    *reinterpret_cast<bf16x8*>(AL + off) = lv;
}

// ---- init out with D*x (+ fac=1 fix at t=0); conv adds 2*sum on top ----
__global__ __launch_bounds__(256) void initout(const float* __restrict__ x,
                                               const float* __restrict__ K,
                                               const float* __restrict__ Dp,
                                               float* __restrict__ out) {
    const int i = blockIdx.x * 256 + threadIdx.x;   // float4 index
    const float D = Dp[0];
    const float4 v = reinterpret_cast<const float4*>(x)[i];
    float4 o = {D * v.x, D * v.y, D * v.z, D * v.w};
    if ((i & 1023) == 0) o.x -= K[0] * v.x;          // t==0: fac 1 not 2
    reinterpret_cast<float4*>(out)[i] = o;
}

// ---- MFMA conv: block = 64t x 128b, 4 waves of 32t x 64b; pair+eighth split
__global__ __launch_bounds__(256) void convm(const short* __restrict__ XH,
                                             const short* __restrict__ XL,
                                             const short* __restrict__ AH,
                                             const short* __restrict__ AL,
                                             float* __restrict__ out) {
    const int bx = blockIdx.x;
    const int pr = bx & 31, bt = (bx >> 5) & 1, h = bx >> 6;
    const int tid = threadIdx.x;
    const int w = tid >> 6, lane = tid & 63;
    const int wr = w & 1, wc = w >> 1;
    const int tA = pr, tB = 63 - pr;
    const int nA = 2 * tA + 2;                 // chunks of tile A; total 130/pair
    const int lo = (130 * h) >> 3, hi = (130 * (h + 1)) >> 3;
    const int bcol0 = bt * 128 + wc * 64;
    const int blkbase = bcol0 >> 4;
    const int lrow = (lane >> 4) << 2;
    const int lcol = lane & 15;

    f32x4 acc[2][4];
#pragma unroll
    for (int r = 0; r < 2; ++r)
#pragma unroll
        for (int c4 = 0; c4 < 4; ++c4) acc[r][c4] = f32x4{0.f, 0.f, 0.f, 0.f};

    int cur = -1, tpos = 0;

    auto flushf = [&]() {
        const int ft = cur * 64 + wr * 32;
#pragma unroll
        for (int r = 0; r < 2; ++r)
#pragma unroll
            for (int c4 = 0; c4 < 4; ++c4)
#pragma unroll
                for (int e = 0; e < 4; ++e) {
                    atomicAdd(&out[(bcol0 + c4 * 16 + lcol) * LENGTH + ft + r * 16 + lrow + e],
                              2.0f * acc[r][c4][e]);
                    acc[r][c4][e] = 0.f;
                }
    };

    for (int idx = lo; idx < hi; ++idx) {
        const int tile = (idx < nA) ? tA : tB;
        const int cc   = (idx < nA) ? idx : idx - nA;
        if (tile != cur) {
            if (cur >= 0) flushf();
            cur = tile;
            tpos = tile * 64 + wr * 32;
        }
        const int sc = cc * 32;
        const int xoff = ((cc * 16 + blkbase) * 64 + lane) * 8;
        bf16x8 bh[4], bl[4];
#pragma unroll
        for (int c4 = 0; c4 < 4; ++c4) {
            bh[c4] = *reinterpret_cast<const bf16x8*>(XH + xoff + c4 * 512);
            bl[c4] = *reinterpret_cast<const bf16x8*>(XL + xoff + c4 * 512);
        }
        const int d0 = tpos - sc;
        const int d1 = d0 + 16;
        if (d0 >= 0) {
            const int o0 = ((d0 >> 4) * 64 + lane) * 8;
            const int o1 = ((d1 >> 4) * 64 + lane) * 8;
            const bf16x8 ah0 = *reinterpret_cast<const bf16x8*>(AH + o0);
            const bf16x8 al0 = *reinterpret_cast<const bf16x8*>(AL + o0);
            const bf16x8 ah1 = *reinterpret_cast<const bf16x8*>(AH + o1);
            const bf16x8 al1 = *reinterpret_cast<const bf16x8*>(AL + o1);
#pragma unroll
            for (int c4 = 0; c4 < 4; ++c4) acc[0][c4] = MFMA(ah0, bh[c4], acc[0][c4]);
#pragma unroll
            for (int c4 = 0; c4 < 4; ++c4) acc[1][c4] = MFMA(ah1, bh[c4], acc[1][c4]);
#pragma unroll
            for (int c4 = 0; c4 < 4; ++c4) acc[0][c4] = MFMA(ah0, bl[c4], acc[0][c4]);
#pragma unroll
            for (int c4 = 0; c4 < 4; ++c4) acc[1][c4] = MFMA(ah1, bl[c4], acc[1][c4]);
#pragma unroll
            for (int c4 = 0; c4 < 4; ++c4) acc[0][c4] = MFMA(al0, bh[c4], acc[0][c4]);
#pragma unroll
            for (int c4 = 0; c4 < 4; ++c4) acc[1][c4] = MFMA(al1, bh[c4], acc[1][c4]);
        } else if (d1 >= 0) {
            const int o1 = ((d1 >> 4) * 64 + lane) * 8;
            const bf16x8 ah1 = *reinterpret_cast<const bf16x8*>(AH + o1);
            const bf16x8 al1 = *reinterpret_cast<const bf16x8*>(AL + o1);
#pragma unroll
            for (int c4 = 0; c4 < 4; ++c4) acc[1][c4] = MFMA(ah1, bh[c4], acc[1][c4]);
#pragma unroll
            for (int c4 = 0; c4 < 4; ++c4) acc[1][c4] = MFMA(ah1, bl[c4], acc[1][c4]);
#pragma unroll
            for (int c4 = 0; c4 < 4; ++c4) acc[1][c4] = MFMA(al1, bh[c4], acc[1][c4]);
        }
    }
    if (cur >= 0) flushf();
}

extern "C" void kernel_launch(void* const* d_in, const int* in_sizes, int n_in,
                              void* d_out, int out_size, void* d_ws, size_t ws_size,
                              hipStream_t stream) {
    const float* x  = (const float*)d_in[0];
    const float* A  = (const float*)d_in[1];
    const float* B  = (const float*)d_in[2];
    const float* C  = (const float*)d_in[3];
    const float* Dp = (const float*)d_in[4];
    float* out = (float*)d_out;
    float* ws  = (float*)d_ws;

    float* P2   = ws + WS_P2;
    float* P4   = ws + WS_P4;
    float* P8   = ws + WS_P8;
    float* P16  = ws + WS_P16;
    float* P32  = ws + WS_P32;
    float* P48  = ws + WS_P48;
    float* P64T = ws + WS_P64T;
    float* Wm   = ws + WS_W;
    float* Vm   = ws + WS_V;
    float* K    = ws + WS_K;
    short* XHs  = (short*)(ws + WS_XH);
    short* XLs  = (short*)(ws + WS_XL);
    short* AHs  = (short*)(ws + WS_AH);
    short* ALs  = (short*)(ws + WS_AL);

    xsplit<<<512, 256, 0, stream>>>(x, XHs, XLs);
    mmrow<<<256, 1024, 0, stream>>>(A, A, P2);
    mmrow<<<256, 1024, 0, stream>>>(P2, P2, P4);
    mmrow<<<256, 1024, 0, stream>>>(P4, P4, P8);
    mmrow<<<256, 1024, 0, stream>>>(P8, P8, P16);
    mmrow<<<256, 1024, 0, stream>>>(P16, P16, P32);
    mm2<<<512, 1024, 0, stream>>>(P32, P16, P64T, P48);
    wvgen<<<5, 1024, 0, stream>>>(A, B, C, P16, P32, P48, P64T, Wm, Vm);
    kdot<<<64, 256, 0, stream>>>(Wm, Vm, K);
    afrag<<<64, 256, 0, stream>>>(K, AHs, ALs);
    initout<<<1024, 256, 0, stream>>>(x, K, Dp, out);
    convm<<<512, 256, 0, stream>>>(XHs, XLs, AHs, ALs, out);
}

// Round 4
// 103.830 us; speedup vs baseline: 3.2968x; 1.7026x over previous
//
#include <hip/hip_runtime.h>

// ---------------------------------------------------------------------------
// HiPPO-LegT via scalar-kernel convolution:
//   pred[b][t] = fac_t * sum_{s<=t} k[t-s] x[b][s] + D x[b][t],  k[tau]=C A^tau B
// k factorized: k[64q+r] = (C A^r) . (A^{64q} B) = W[r] . V[q]
//   W: 2 chains x 32 steps (C, C*A^32);  V: 2 chains x 32 steps (A^128 doubling)
// Conv as MFMA GEMM vs Toeplitz T; per-block k-split over 8 waves + LDS reduce,
// coalesced exclusive stores (no atomics), double-buffered fragment prefetch.
// ---------------------------------------------------------------------------

#define LENGTH 4096

// ws layout (float offsets)
#define WS_P2    0
#define WS_P4    65536
#define WS_P8    131072
#define WS_P16   196608
#define WS_P32   262144
#define WS_P64T  327680
#define WS_P128T 393216
#define WS_W     458752   // 64 x 256
#define WS_V     475136   // 64 x 256
#define WS_K     491520   // 4096
#define WS_XH    495616   // 1M shorts = 524288 floats
#define WS_XL    1019904
#define WS_AH    1544192  // 256*64*8 shorts = 65536 floats
#define WS_AL    1609728

typedef __attribute__((ext_vector_type(8))) short bf16x8;
typedef __attribute__((ext_vector_type(4))) float f32x4;
#define MFMA(a, b, c) __builtin_amdgcn_mfma_f32_16x16x32_bf16(a, b, c, 0, 0, 0)

__device__ inline unsigned short f2bf(float f) {
    unsigned int u = __float_as_uint(f);
    return (unsigned short)((u + 0x7FFFu + ((u >> 16) & 1u)) >> 16);
}
__device__ inline void split2(float f, short& h, short& l) {
    unsigned short hu = f2bf(f);
    float fh = __uint_as_float((unsigned int)hu << 16);
    h = (short)hu;
    l = (short)f2bf(f - fh);
}

// ---- 256x256 matmul: Z = X*Y, one row per block, K split over 4 groups ----
__global__ __launch_bounds__(1024) void mmrow(const float* __restrict__ X,
                                              const float* __restrict__ Y,
                                              float* __restrict__ Z) {
    const int i = blockIdx.x, t = threadIdx.x;
    const int j = t & 255, p = t >> 8;
    __shared__ float red[3][256];
    const float* xr = X + i * 256 + 64 * p;
    const float* yc = Y + (64 * p) * 256 + j;
    float a0 = 0.f, a1 = 0.f, a2 = 0.f, a3 = 0.f;
#pragma unroll
    for (int l = 0; l < 64; l += 4) {
        a0 = fmaf(xr[l + 0], yc[(l + 0) * 256], a0);
        a1 = fmaf(xr[l + 1], yc[(l + 1) * 256], a1);
        a2 = fmaf(xr[l + 2], yc[(l + 2) * 256], a2);
        a3 = fmaf(xr[l + 3], yc[(l + 3) * 256], a3);
    }
    float s = (a0 + a1) + (a2 + a3);
    if (p) red[p - 1][j] = s;
    __syncthreads();
    if (p == 0) Z[i * 256 + j] = s + red[0][j] + red[1][j] + red[2][j];
}

// ---- transposed-store matmul: P64T[j][i] = (P32*P32)[i][j] ----
__global__ __launch_bounds__(1024) void mm2(const float* __restrict__ P32,
                                            float* __restrict__ P64T) {
    const int i = blockIdx.x, t = threadIdx.x;
    const int j = t & 255, p = t >> 8;
    __shared__ float red[3][256];
    const float* xr = P32 + i * 256 + 64 * p;
    const float* yc = P32 + (64 * p) * 256 + j;
    float a0 = 0.f, a1 = 0.f, a2 = 0.f, a3 = 0.f;
#pragma unroll
    for (int l = 0; l < 64; l += 4) {
        a0 = fmaf(xr[l + 0], yc[(l + 0) * 256], a0);
        a1 = fmaf(xr[l + 1], yc[(l + 1) * 256], a1);
        a2 = fmaf(xr[l + 2], yc[(l + 2) * 256], a2);
        a3 = fmaf(xr[l + 3], yc[(l + 3) * 256], a3);
    }
    float s = (a0 + a1) + (a2 + a3);
    if (p) red[p - 1][j] = s;
    __syncthreads();
    if (p == 0) P64T[j * 256 + i] = s + red[0][j] + red[1][j] + red[2][j];
}

// ---- chains: blocks 0,1 = W (C*A^s, s base 0/32); blocks 2,3 = V (A^128 doubling)
__global__ __launch_bounds__(1024) void wvgen(const float* __restrict__ A,
                                              const float* __restrict__ B,
                                              const float* __restrict__ C,
                                              const float* __restrict__ P32,
                                              const float* __restrict__ P64T,
                                              const float* __restrict__ P128T,
                                              float* __restrict__ W,
                                              float* __restrict__ V) {
    const int t = threadIdx.x;
    const int bid = blockIdx.x;
    const int j = t & 255, p = t >> 8;
    __shared__ float cur[256];
    __shared__ float red[4][256];

    if (bid < 2) {
        // ---- W chain ----
        float areg[64];
#pragma unroll
        for (int ii = 0; ii < 64; ++ii) areg[ii] = A[(64 * p + ii) * 256 + j];

        if (bid == 0) {
            if (t < 256) cur[t] = C[t];
            __syncthreads();
        } else {
            float s0 = 0.f, s1 = 0.f, s2 = 0.f, s3 = 0.f;
#pragma unroll 4
            for (int ii = 0; ii < 64; ii += 4) {
                s0 = fmaf(C[64 * p + ii + 0], P32[(64 * p + ii + 0) * 256 + j], s0);
                s1 = fmaf(C[64 * p + ii + 1], P32[(64 * p + ii + 1) * 256 + j], s1);
                s2 = fmaf(C[64 * p + ii + 2], P32[(64 * p + ii + 2) * 256 + j], s2);
                s3 = fmaf(C[64 * p + ii + 3], P32[(64 * p + ii + 3) * 256 + j], s3);
            }
            red[p][j] = (s0 + s1) + (s2 + s3);
            __syncthreads();
            if (p == 0) cur[j] = red[0][j] + red[1][j] + red[2][j] + red[3][j];
            __syncthreads();
        }
        const int base = bid * 32;
        if (p == 0) W[base * 256 + j] = cur[j];
        for (int r = 1; r < 32; ++r) {
            float s0 = 0.f, s1 = 0.f, s2 = 0.f, s3 = 0.f;
#pragma unroll
            for (int m = 0; m < 16; ++m) {
                float4 c4 = *reinterpret_cast<const float4*>(&cur[64 * p + 4 * m]);
                s0 = fmaf(c4.x, areg[4 * m + 0], s0);
                s1 = fmaf(c4.y, areg[4 * m + 1], s1);
                s2 = fmaf(c4.z, areg[4 * m + 2], s2);
                s3 = fmaf(c4.w, areg[4 * m + 3], s3);
            }
            red[p][j] = (s0 + s1) + (s2 + s3);
            __syncthreads();
            if (p == 0) {
                float s = red[0][j] + red[1][j] + red[2][j] + red[3][j];
                cur[j] = s;
                W[(base + r) * 256 + j] = s;
            }
            __syncthreads();
        }
    } else {
        // ---- V chain: bid2 emits V[0,2,..62]; bid3 emits V[1,3,..63] ----
        const int i = j;
        float mreg[64];
#pragma unroll
        for (int jj = 0; jj < 64; ++jj) mreg[jj] = P128T[(64 * p + jj) * 256 + i];
        if (t < 256) cur[t] = B[t];
        __syncthreads();

        if (bid == 3) {   // one A^64 step from global P64T
            float s0 = 0.f, s1 = 0.f, s2 = 0.f, s3 = 0.f;
#pragma unroll 4
            for (int jj = 0; jj < 64; jj += 4) {
                s0 = fmaf(P64T[(64 * p + jj + 0) * 256 + i], cur[64 * p + jj + 0], s0);
                s1 = fmaf(P64T[(64 * p + jj + 1) * 256 + i], cur[64 * p + jj + 1], s1);
                s2 = fmaf(P64T[(64 * p + jj + 2) * 256 + i], cur[64 * p + jj + 2], s2);
                s3 = fmaf(P64T[(64 * p + jj + 3) * 256 + i], cur[64 * p + jj + 3], s3);
            }
            red[p][i] = (s0 + s1) + (s2 + s3);
            __syncthreads();
            if (p == 0) cur[i] = red[0][i] + red[1][i] + red[2][i] + red[3][i];
            __syncthreads();
        }
        const int off = bid - 2;
        for (int m = 0; m < 32; ++m) {
            if (p == 0) V[(2 * m + off) * 256 + i] = cur[i];
            if (m == 31) break;
            float s0 = 0.f, s1 = 0.f, s2 = 0.f, s3 = 0.f;
#pragma unroll
            for (int mm = 0; mm < 16; ++mm) {
                float4 c4 = *reinterpret_cast<const float4*>(&cur[64 * p + 4 * mm]);
                s0 = fmaf(c4.x, mreg[4 * mm + 0], s0);
                s1 = fmaf(c4.y, mreg[4 * mm + 1], s1);
                s2 = fmaf(c4.z, mreg[4 * mm + 2], s2);
                s3 = fmaf(c4.w, mreg[4 * mm + 3], s3);
            }
            red[p][i] = (s0 + s1) + (s2 + s3);
            __syncthreads();
            if (p == 0) cur[i] = red[0][i] + red[1][i] + red[2][i] + red[3][i];
            __syncthreads();
        }
    }
}

// ---- K dots: K[64q + r] = W[r] . V[q], block = q ----
__global__ __launch_bounds__(256) void kdot(const float* __restrict__ W,
                                            const float* __restrict__ V,
                                            float* __restrict__ K) {
    const int q = blockIdx.x, tid = threadIdx.x;
    const int r = tid & 63, p = tid >> 6;
    __shared__ float Wl[64 * 257];
    __shared__ float Vl[256];
    __shared__ float red[4][64];
    for (int u = 0; u < 64; ++u) Wl[u * 257 + tid] = W[u * 256 + tid];
    Vl[tid] = V[q * 256 + tid];
    __syncthreads();
    float s0 = 0.f, s1 = 0.f;
#pragma unroll
    for (int m = 0; m < 64; m += 2) {
        s0 = fmaf(Wl[r * 257 + 64 * p + m + 0], Vl[64 * p + m + 0], s0);
        s1 = fmaf(Wl[r * 257 + 64 * p + m + 1], Vl[64 * p + m + 1], s1);
    }
    red[p][r] = s0 + s1;
    __syncthreads();
    if (tid < 64) K[q * 64 + tid] = red[0][tid] + red[1][tid] + red[2][tid] + red[3][tid];
}

// ---- pack x into B-fragment layout, bf16 hi+lo ----
__global__ __launch_bounds__(256) void xsplit(const float* __restrict__ x,
                                              short* __restrict__ XH,
                                              short* __restrict__ XL) {
    const int w = threadIdx.x >> 6, lane = threadIdx.x & 63;
    const int p = blockIdx.x * 4 + w;          // 0..2047
    const int c = p >> 4, blk = p & 15;
    const int b = blk * 16 + (lane & 15);
    const int s0 = c * 32 + 8 * (lane >> 4);
    const float4 v0 = reinterpret_cast<const float4*>(&x[b * LENGTH + s0])[0];
    const float4 v1 = reinterpret_cast<const float4*>(&x[b * LENGTH + s0])[1];
    const float f[8] = {v0.x, v0.y, v0.z, v0.w, v1.x, v1.y, v1.z, v1.w};
    bf16x8 hv, lv;
#pragma unroll
    for (int e = 0; e < 8; ++e) {
        short h, l;
        split2(f[e], h, l);
        hv[e] = h; lv[e] = l;
    }
    const int off = (p * 64 + lane) * 8;
    *reinterpret_cast<bf16x8*>(XH + off) = hv;
    *reinterpret_cast<bf16x8*>(XL + off) = lv;
}

// ---- Toeplitz A-fragment tables: entry m = lag d0 = 16m ----
__global__ __launch_bounds__(256) void afrag(const float* __restrict__ K,
                                             short* __restrict__ AH,
                                             short* __restrict__ AL) {
    const int m = blockIdx.x * 4 + (threadIdx.x >> 6);
    const int lane = threadIdx.x & 63;
    bf16x8 hv, lv;
#pragma unroll
    for (int e = 0; e < 8; ++e) {
        const int kidx = 16 * m + (lane & 15) - 8 * (lane >> 4) - e;
        const float kv = (kidx >= 0) ? K[kidx] : 0.f;
        short h, l;
        split2(kv, h, l);
        hv[e] = h; lv[e] = l;
    }
    const int off = (m * 64 + lane) * 8;
    *reinterpret_cast<bf16x8*>(AH + off) = hv;
    *reinterpret_cast<bf16x8*>(AL + off) = lv;
}

// ---- MFMA conv: 256 blocks = 32 pairs x 8 btiles(32b); 8 waves k-split the
// 130 s-chunks of the pair's two 64t x 32b tiles; LDS reduce; coalesced store.
struct Frag {
    bf16x8 bh0, bh1, bl0, bl1;
    bf16x8 ah0, ah1, ah2, ah3, al0, al1, al2, al3;
    int d0, tile;
};

__global__ __launch_bounds__(512) void convm(const short* __restrict__ XH,
                                             const short* __restrict__ XL,
                                             const short* __restrict__ AH,
                                             const short* __restrict__ AL,
                                             const float* __restrict__ x,
                                             const float* __restrict__ Dp,
                                             float* __restrict__ out) {
    const int pr = blockIdx.x & 31;
    const int bt = blockIdx.x >> 5;
    const int tid = threadIdx.x;
    const int w = tid >> 6, lane = tid & 63;
    const int tA64 = pr * 64, tB64 = (63 - pr) * 64;
    const int nA = 2 * pr + 2;                 // chunks of tile A; total 130
    const int bt2 = bt * 2;

    __shared__ float lds[16 * 64 * 34];        // [w*2+tile][row 64][col 32] pad 34

    f32x4 acc[2][4][2];
#pragma unroll
    for (int t_ = 0; t_ < 2; ++t_)
#pragma unroll
        for (int r_ = 0; r_ < 4; ++r_)
#pragma unroll
            for (int c_ = 0; c_ < 2; ++c_) acc[t_][r_][c_] = f32x4{0.f, 0.f, 0.f, 0.f};

#define LOADF(F, IDX_) do {                                                    \
        const int i_ = (IDX_);                                                 \
        const int tl_ = (i_ < nA) ? 0 : 1;                                     \
        const int cc_ = i_ - (tl_ ? nA : 0);                                   \
        const int xo_ = ((cc_ * 16 + bt2) * 64 + lane) * 8;                    \
        F.bh0 = *reinterpret_cast<const bf16x8*>(XH + xo_);                    \
        F.bh1 = *reinterpret_cast<const bf16x8*>(XH + xo_ + 512);              \
        F.bl0 = *reinterpret_cast<const bf16x8*>(XL + xo_);                    \
        F.bl1 = *reinterpret_cast<const bf16x8*>(XL + xo_ + 512);              \
        const int d_ = (tl_ ? tB64 : tA64) - cc_ * 32;                         \
        F.d0 = d_; F.tile = tl_;                                               \
        const int m0_ = (d_ > 0 ? d_ : 0) >> 4;                                \
        const int m1_ = (d_ + 16 > 0 ? d_ + 16 : 0) >> 4;                      \
        const int m2_ = (d_ + 32 > 0 ? d_ + 32 : 0) >> 4;                      \
        const int m3_ = (d_ + 48 > 0 ? d_ + 48 : 0) >> 4;                      \
        F.ah0 = *reinterpret_cast<const bf16x8*>(AH + (m0_ * 64 + lane) * 8);  \
        F.al0 = *reinterpret_cast<const bf16x8*>(AL + (m0_ * 64 + lane) * 8);  \
        F.ah1 = *reinterpret_cast<const bf16x8*>(AH + (m1_ * 64 + lane) * 8);  \
        F.al1 = *reinterpret_cast<const bf16x8*>(AL + (m1_ * 64 + lane) * 8);  \
        F.ah2 = *reinterpret_cast<const bf16x8*>(AH + (m2_ * 64 + lane) * 8);  \
        F.al2 = *reinterpret_cast<const bf16x8*>(AL + (m2_ * 64 + lane) * 8);  \
        F.ah3 = *reinterpret_cast<const bf16x8*>(AH + (m3_ * 64 + lane) * 8);  \
        F.al3 = *reinterpret_cast<const bf16x8*>(AL + (m3_ * 64 + lane) * 8);  \
    } while (0)

#define ONER(F, T, R, AHF, ALF)                                                \
        if (F.d0 + 16 * R >= 0) {                                              \
            acc[T][R][0] = MFMA(F.AHF, F.bh0, acc[T][R][0]);                   \
            acc[T][R][1] = MFMA(F.AHF, F.bh1, acc[T][R][1]);                   \
            acc[T][R][0] = MFMA(F.AHF, F.bl0, acc[T][R][0]);                   \
            acc[T][R][1] = MFMA(F.AHF, F.bl1, acc[T][R][1]);                   \
            acc[T][R][0] = MFMA(F.ALF, F.bh0, acc[T][R][0]);                   \
            acc[T][R][1] = MFMA(F.ALF, F.bh1, acc[T][R][1]);                   \
        }

#define APPLY(F) do {                                                          \
        if (F.tile == 0) {                                                     \
            ONER(F, 0, 0, ah0, al0) ONER(F, 0, 1, ah1, al1)                    \
            ONER(F, 0, 2, ah2, al2) ONER(F, 0, 3, ah3, al3)                    \
        } else {                                                               \
            ONER(F, 1, 0, ah0, al0) ONER(F, 1, 1, ah1, al1)                    \
            ONER(F, 1, 2, ah2, al2) ONER(F, 1, 3, ah3, al3)                    \
        }                                                                      \
    } while (0)

    Frag f0, f1;
    LOADF(f0, w);
    int idx = w;
    while (true) {
        const int n1 = idx + 8;
        const bool h1 = n1 < 130;
        if (h1) LOADF(f1, n1);
        APPLY(f0);
        if (!h1) break;
        const int n2 = n1 + 8;
        const bool h2 = n2 < 130;
        if (h2) LOADF(f0, n2);
        APPLY(f1);
        if (!h2) break;
        idx = n2;
    }

    // flush per-wave partials to LDS
    const int lq = lane >> 4, lr = lane & 15;
#pragma unroll
    for (int t_ = 0; t_ < 2; ++t_)
#pragma unroll
        for (int r_ = 0; r_ < 4; ++r_)
#pragma unroll
            for (int c_ = 0; c_ < 2; ++c_)
#pragma unroll
                for (int e_ = 0; e_ < 4; ++e_)
                    lds[((w * 2 + t_) * 64 + (r_ * 16 + lq * 4 + e_)) * 34 +
                        (c_ * 16 + lr)] = acc[t_][r_][c_][e_];
    __syncthreads();

    // reduce 8 waves + fold D*x + t0 fix; coalesced float4 stores
    const float D = Dp[0];
    const int b = tid >> 4;
    const int t4 = (tid & 15) * 4;
#pragma unroll
    for (int t_ = 0; t_ < 2; ++t_) {
        const int tbase = t_ ? tB64 : tA64;
        float s0 = 0.f, s1 = 0.f, s2 = 0.f, s3 = 0.f;
#pragma unroll
        for (int w_ = 0; w_ < 8; ++w_) {
            const float* lp = &lds[((w_ * 2 + t_) * 64 + t4) * 34 + b];
            s0 += lp[0]; s1 += lp[34]; s2 += lp[68]; s3 += lp[102];
        }
        const int g = (bt * 32 + b) * LENGTH + tbase + t4;
        const float4 xv = *reinterpret_cast<const float4*>(x + g);
        float4 o;
        o.x = 2.f * s0 + D * xv.x;
        o.y = 2.f * s1 + D * xv.y;
        o.z = 2.f * s2 + D * xv.z;
        o.w = 2.f * s3 + D * xv.w;
        if (tbase == 0 && t4 == 0) o.x -= s0;   // t==0: fac is 1, not 2
        *reinterpret_cast<float4*>(out + g) = o;
    }
}

extern "C" void kernel_launch(void* const* d_in, const int* in_sizes, int n_in,
                              void* d_out, int out_size, void* d_ws, size_t ws_size,
                              hipStream_t stream) {
    const float* x  = (const float*)d_in[0];
    const float* A  = (const float*)d_in[1];
    const float* B  = (const float*)d_in[2];
    const float* C  = (const float*)d_in[3];
    const float* Dp = (const float*)d_in[4];
    float* out = (float*)d_out;
    float* ws  = (float*)d_ws;

    float* P2    = ws + WS_P2;
    float* P4    = ws + WS_P4;
    float* P8    = ws + WS_P8;
    float* P16   = ws + WS_P16;
    float* P32   = ws + WS_P32;
    float* P64T  = ws + WS_P64T;
    float* P128T = ws + WS_P128T;
    float* Wm    = ws + WS_W;
    float* Vm    = ws + WS_V;
    float* K     = ws + WS_K;
    short* XHs   = (short*)(ws + WS_XH);
    short* XLs   = (short*)(ws + WS_XL);
    short* AHs   = (short*)(ws + WS_AH);
    short* ALs   = (short*)(ws + WS_AL);

    xsplit<<<512, 256, 0, stream>>>(x, XHs, XLs);
    mmrow<<<256, 1024, 0, stream>>>(A, A, P2);
    mmrow<<<256, 1024, 0, stream>>>(P2, P2, P4);
    mmrow<<<256, 1024, 0, stream>>>(P4, P4, P8);
    mmrow<<<256, 1024, 0, stream>>>(P8, P8, P16);
    mmrow<<<256, 1024, 0, stream>>>(P16, P16, P32);
    mm2<<<256, 1024, 0, stream>>>(P32, P64T);
    mmrow<<<256, 1024, 0, stream>>>(P64T, P64T, P128T);
    wvgen<<<4, 1024, 0, stream>>>(A, B, C, P32, P64T, P128T, Wm, Vm);
    kdot<<<64, 256, 0, stream>>>(Wm, Vm, K);
    afrag<<<64, 256, 0, stream>>>(K, AHs, ALs);
    convm<<<256, 512, 0, stream>>>(XHs, XLs, AHs, ALs, x, Dp, out);
}